// Round 10
// baseline (374.733 us; speedup 1.0000x reference)
//
#include <hip/hip_runtime.h>
#include <hip/hip_bf16.h>
#include <cmath>

#define NN 200000
#define NE 600000
#define NG 1024
#define HH 512
#define ES 896            // efs slots per graph (max cnt ~745, 6.5σ margin)

typedef short short8 __attribute__((ext_vector_type(8)));
typedef short short4v __attribute__((ext_vector_type(4)));
typedef float f32x4 __attribute__((ext_vector_type(4)));
typedef float f32x2 __attribute__((ext_vector_type(2)));
typedef float f32x16 __attribute__((ext_vector_type(16)));

__device__ __forceinline__ unsigned short f2bf(float f){
  unsigned u = __float_as_uint(f);
  u += 0x7fffu + ((u >> 16) & 1u);
  return (unsigned short)(u >> 16);
}
__device__ __forceinline__ float bf2f(unsigned short h){
  return __uint_as_float(((unsigned)h) << 16);
}

// packed f32x8 -> bf16x8 (RTNE)
__device__ __forceinline__ short8 cvt8pk(float4 a, float4 b){
  union { short8 s; __hip_bfloat162 h[4]; } u;
  u.h[0] = __float22bfloat162_rn(make_float2(a.x, a.y));
  u.h[1] = __float22bfloat162_rn(make_float2(a.z, a.w));
  u.h[2] = __float22bfloat162_rn(make_float2(b.x, b.y));
  u.h[3] = __float22bfloat162_rn(make_float2(b.z, b.w));
  return u.s;
}

// analytic gelu (GEMM epilogues only — 1M elements total)
__device__ __forceinline__ float gelu_f(float x){
  float p = __builtin_fmaf(x*x, -0.10294325f, -2.3022085f);
  float e = __builtin_amdgcn_exp2f(x * p);
  return x * __builtin_amdgcn_rcpf(1.0f + e);
}

// ---- packed fp32 (VOP3P; rate-neutral vs scalar but halves inst count) ----
#define PKFMA3(d,a,b,c) asm("v_pk_fma_f32 %0, %1, %2, %3" : "=v"(d) : "v"(a), "v"(b), "v"(c))
#define PKFMA_IP(p,s,k) asm("v_pk_fma_f32 %0, %0, %1, %2" : "+v"(p) : "v"(s), "v"(k))
#define PKADD_IP(d,a)   asm("v_pk_add_f32 %0, %0, %1"     : "+v"(d) : "v"(a))

// gelu accumulate; bias already inside y (folded into MFMA C operand).
//   y = x*ISQ (pre-scaled);  s = y^2-1;  P(s)=G(x^2), P(-1)=0
//   aX += y; aP += P.  Final: sum gelu = FXH*aX + aP
#define G2(y_) { \
  f32x2 s_; PKFMA3(s_, y_, y_, n1); \
  f32x2 p_; PKFMA3(p_, s_, K6, K5); \
  PKFMA_IP(p_, s_, K4); PKFMA_IP(p_, s_, K3); \
  PKFMA_IP(p_, s_, K2); PKFMA_IP(p_, s_, K1); \
  PKFMA_IP(p_, s_, K0); \
  PKADD_IP(aX, y_); PKADD_IP(aP, p_); }

#define COEFS \
  const f32x2 K0 = {c0,c0}, K1 = {c1,c1}, K2 = {c2,c2}, K3 = {c3,c3}; \
  const f32x2 K4 = {c4,c4}, K5 = {c5,c5}, K6 = {c6,c6}; \
  const f32x2 n1 = {-1.f,-1.f};

#define ISQ 0.56568542494924f    // sqrt(2)/2.5 : y = x*ISQ, s=y^2-1 spans x^2 in [0,6.25]
#define FXH 0.88388347648318f    // 0.5x = FXH*y

// ========== kpre: weights + nstart + cnt/out init + nf48 prepack + B transpose-split ===
__global__ __launch_bounds__(256) void kpre(
    const float* __restrict__ nfw1, const float* __restrict__ nfb1,
    const float* __restrict__ nfg1, const float* __restrict__ nfbe1,
    const float* __restrict__ efw1, const float* __restrict__ efb1,
    const float* __restrict__ efg1, const float* __restrict__ efbe1,
    const float* __restrict__ w2n, const float* __restrict__ w2e,
    const float* __restrict__ ow1, const float* __restrict__ ow2,
    const float* __restrict__ ob3, float* __restrict__ outd,
    unsigned short* __restrict__ w1n48T, unsigned short* __restrict__ w1eT16,
    float* __restrict__ b1n_s, float* __restrict__ b1e_s,
    const int* __restrict__ bidx, int* __restrict__ nstart,
    int* __restrict__ cnt,
    const float* __restrict__ nf, const float* __restrict__ dp,
    const int* __restrict__ ny,
    unsigned short* __restrict__ nf48,
    unsigned short* __restrict__ Bh1, unsigned short* __restrict__ Bl1,
    unsigned short* __restrict__ Bh2, unsigned short* __restrict__ Bl2,
    unsigned short* __restrict__ Bh3, unsigned short* __restrict__ Bl3){
  const float rs = 0.99999500003750f;   // 1/sqrt(1+1e-5)
  int b = blockIdx.x, t = threadIdx.x;
  if (b < 2){
    int c = b*256 + t;
    float sc = efg1[c]*rs*ISQ;
#pragma unroll
    for (int k=0;k<16;++k) w1eT16[c*16+k] = f2bf(efw1[k*HH+c]*sc);
    b1e_s[c] = (efb1[c]*efg1[c]*rs + efbe1[c])*ISQ;
  } else if (b < 4){
    int c = (b-2)*256 + t;
    float sc = nfg1[c]*rs*ISQ;
#pragma unroll
    for (int k=0;k<48;++k)
      w1n48T[c*48+k] = (k < 41) ? f2bf(nfw1[k*HH+c]*sc) : (unsigned short)0;
    b1n_s[c] = (nfb1[c]*nfg1[c]*rs + nfbe1[c])*ISQ;
  } else if (b < 786){
    int i = (b-4)*256 + t;
    if (i < NN){
      int g0 = bidx[i];
      int g1 = (i+1 < NN) ? bidx[i+1] : NG;
      for (int g = g0+1; g <= g1; ++g) nstart[g] = i+1;
      if (i == 0) for (int g = 0; g <= g0; ++g) nstart[g] = 0;
    }
  } else if (b == 786){
    cnt[t] = 0; cnt[t+256] = 0; cnt[t+512] = 0; cnt[t+768] = 0;
    // d_out init with final bias (G3 epilogue atomically accumulates into it)
    float bb0 = ob3[0], bb1 = ob3[1];
    for (int i = t; i < 2048; i += 256) outd[i] = (i & 1) ? bb1 : bb0;
  } else if (b < 1569){
    int r = (b-787)*256 + t;
    if (r < NN){
      const float4* ap = (const float4*)(nf + (size_t)r*32);
      unsigned short v[48];
      union { short8 s; unsigned short u[8]; } cv;
#pragma unroll
      for (int p2=0; p2<4; ++p2){
        cv.s = cvt8pk(ap[2*p2], ap[2*p2+1]);
#pragma unroll
        for (int j=0;j<8;++j) v[p2*8+j] = cv.u[j];
      }
      unsigned short db = f2bf(dp[r]);
      int cls = ny[r];
#pragma unroll
      for (int j=0;j<9;++j) v[32+j] = (cls==j) ? db : (unsigned short)0;
#pragma unroll
      for (int j=41;j<48;++j) v[j] = 0;
      unsigned short* op = nf48 + (size_t)r*48;
#pragma unroll
      for (int p2=0; p2<6; ++p2) *(short8*)(op + p2*8) = *(short8*)&v[p2*8];
    }
  } else {
    // B-plane transpose-split: 64x64 fp32 tile -> Th/Tl [c][k] K-major bf16
    __shared__ float lds[64][65];
    int tb = b - 1569;
    int which, KK; unsigned short *Th, *Tl;
    if (tb < 128){ which = 1; KK = 1024; Th = Bh1; Tl = Bl1; }
    else if (tb < 192){ which = 2; KK = 512; Th = Bh2; Tl = Bl2; tb -= 128; }
    else { which = 3; KK = 512; Th = Bh3; Tl = Bl3; tb -= 192; }
    const int kt = tb >> 3, ct = tb & 7;
    const int k0 = kt*64, c0 = ct*64;
    const int tr = t >> 4, tc = (t & 15)*4;
#pragma unroll
    for (int i=0;i<4;++i){
      int row = tr + i*16;           // k within tile
      int gk = k0 + row;
      const float* src;
      if (which == 1) src = (gk < 512) ? (w2n + (size_t)gk*HH) : (w2e + (size_t)(gk-512)*HH);
      else if (which == 2) src = ow1 + (size_t)gk*HH;
      else src = ow2 + (size_t)gk*HH;
      float4 v = *(const float4*)(src + c0 + tc);
      lds[row][tc+0] = v.x; lds[row][tc+1] = v.y;
      lds[row][tc+2] = v.z; lds[row][tc+3] = v.w;
    }
    __syncthreads();
#pragma unroll
    for (int i=0;i<4;++i){
      int c = tr + i*16;             // col within tile
      short4v h4, l4;
#pragma unroll
      for (int j=0;j<4;++j){
        float vv = lds[tc+j][c];
        unsigned short h = f2bf(vv);
        h4[j] = (short)h;
        l4[j] = (short)f2bf(vv - bf2f(h));
      }
      size_t o = (size_t)(c0 + c)*KK + k0 + tc;
      *(short4v*)(Th + o) = h4;
      *(short4v*)(Tl + o) = l4;
    }
  }
}

// ========== kscatter: two-level scatter; phase-2 writes SORTED bf16 edge feats =======
__global__ __launch_bounds__(1024) void kscatter(const int* __restrict__ eidx,
    const int* __restrict__ bidx, const float* __restrict__ ef,
    int* __restrict__ eg, int* __restrict__ cnt, unsigned short* __restrict__ efs){
  __shared__ int h[NG];
  __shared__ int base[NG];
  const int b = blockIdx.x, t = threadIdx.x;
  h[t] = 0;
  __syncthreads();
  const int per = NE / 64;            // 9375, exact
  const int lo = b*per, hi = lo + per;
  for (int e = lo + t; e < hi; e += 1024){
    int g = bidx[eidx[e]];
    eg[e] = g;
    atomicAdd(&h[g], 1);
  }
  __syncthreads();
  int c = h[t];
  if (c > 0) base[t] = atomicAdd(&cnt[t], c);
  h[t] = 0;
  __syncthreads();
  for (int e = lo + t; e < hi; e += 1024){
    int g = eg[e];
    int p = base[g] + atomicAdd(&h[g], 1);
    if (p < ES){
      const float4* ap = (const float4*)(ef + (size_t)e*16);
      float4 a0 = ap[0], a1 = ap[1], a2 = ap[2], a3 = ap[3];
      unsigned short* op = efs + ((size_t)g*ES + p)*16;
      *(short8*)op       = cvt8pk(a0, a1);
      *(short8*)(op + 8) = cvt8pk(a2, a3);
    }
  }
}

// ========== kmain2: edge(bid<2048, contiguous efs, prefetch-pipelined) + node ==========
// 8 waves x 32 cols; bias in MFMA C; deg-6 pk-Horner gelu (coeffs as kernel args)
__global__ __launch_bounds__(512) void kmain2(
    const unsigned short* __restrict__ efs, const int* __restrict__ cnt,
    const unsigned short* __restrict__ w1eT16, const float* __restrict__ b1e_s,
    const unsigned short* __restrict__ nf48, const int* __restrict__ nstart,
    const unsigned short* __restrict__ w1n48T, const float* __restrict__ b1n_s,
    float c0, float c1, float c2, float c3, float c4, float c5, float c6,
    unsigned short* __restrict__ Sh, unsigned short* __restrict__ Sl){
  const int t = threadIdx.x;
  const int lane = t & 63, wid = t >> 6;
  const int hi = lane >> 5, ln31 = lane & 31;
  COEFS;
  f32x2 aX = {0.f,0.f}, aP = {0.f,0.f};
  if (blockIdx.x < 2048){
    // ---------------- EDGE (contiguous sorted features; 1-deep prefetch) ----------------
    const int g = blockIdx.x >> 1;
    const int col = ((blockIdx.x & 1) << 8) + (wid << 5) + ln31;
    short8 bfr = *(const short8*)(w1eT16 + col*16 + (hi<<3));
    const float bv = b1e_s[col];
    f32x16 bias16;
#pragma unroll
    for (int i=0;i<16;++i) bias16[i] = bv;
    const int s1 = min(cnt[g], ES);
    const unsigned short* ep = efs + (size_t)g*(ES*16) + ln31*16 + (hi<<3);
    if (s1 > 0){
      const int nfull = s1 >> 5;
      int rb = 0;
      // prefetch chunk 0 (rows beyond s1 read garbage from padded buffer; masked later)
      short8 afc = *(const short8*)(ep);
      for (int ch=0; ch<nfull; ++ch, rb += 32){
        short8 afn = *(const short8*)(ep + (size_t)(rb+32)*16);  // padded over-read ok
        f32x16 acc = __builtin_amdgcn_mfma_f32_32x32x16_bf16(afc, bfr, bias16, 0, 0, 0);
#pragma unroll
        for (int i=0;i<8;++i){
          f32x2 y = {acc[2*i], acc[2*i+1]};
          G2(y);
        }
        afc = afn;
      }
      if (rb < s1){
        f32x16 acc = __builtin_amdgcn_mfma_f32_32x32x16_bf16(afc, bfr, bias16, 0, 0, 0);
        const int vr = s1 - rb;
#pragma unroll
        for (int i=0;i<8;++i){
          int r0 = ((2*i)&3) + (((2*i)>>2)<<3) + (hi<<2);
          f32x2 y = { (r0 < vr) ? acc[2*i] : 0.f,
                      (r0+1 < vr) ? acc[2*i+1] : 0.f };
          G2(y);
        }
      }
    }
    float ssum = __builtin_fmaf(FXH, aX[0]+aX[1], aP[0]+aP[1]);
    ssum += __shfl_xor(ssum, 32);
    if (lane < 32){
      size_t o = (size_t)g*1024 + 512 + col;
      unsigned short h = f2bf(ssum);
      Sh[o] = h; Sl[o] = f2bf(ssum - bf2f(h));
    }
  } else {
    // ---------------- NODE ----------------
    const int b2 = blockIdx.x - 2048;
    const int g = b2 >> 1;
    const int col = ((b2 & 1) << 8) + (wid << 5) + ln31;
    const unsigned short* bp = w1n48T + col*48 + (hi<<3);
    short8 b0 = *(const short8*)(bp);
    short8 b1 = *(const short8*)(bp + 16);
    short8 b2f = *(const short8*)(bp + 32);
    const float bv = b1n_s[col];
    f32x16 bias16;
#pragma unroll
    for (int i=0;i<16;++i) bias16[i] = bv;
    const int s0r = nstart[g], s1 = nstart[g+1];
    const int nch = (s1 - s0r + 31) >> 5;
    for (int ch=0; ch<nch; ++ch){
      const int rb = s0r + ch*32;
      int ar = min(rb + ln31, s1-1);
      const unsigned short* apn = nf48 + (size_t)ar*48 + (hi<<3);
      short8 a0 = *(const short8*)(apn);
      short8 a1 = *(const short8*)(apn + 16);
      short8 a2 = *(const short8*)(apn + 32);
      f32x16 acc = __builtin_amdgcn_mfma_f32_32x32x16_bf16(a0, b0, bias16, 0, 0, 0);
      acc = __builtin_amdgcn_mfma_f32_32x32x16_bf16(a1, b1, acc, 0, 0, 0);
      acc = __builtin_amdgcn_mfma_f32_32x32x16_bf16(a2, b2f, acc, 0, 0, 0);
      const int vr = s1 - rb;
      if (vr >= 32){
#pragma unroll
        for (int i=0;i<8;++i){
          f32x2 y = {acc[2*i], acc[2*i+1]};
          G2(y);
        }
      } else {
#pragma unroll
        for (int i=0;i<8;++i){
          int r0 = ((2*i)&3) + (((2*i)>>2)<<3) + (hi<<2);
          f32x2 y = { (r0 < vr) ? acc[2*i] : 0.f,
                      (r0+1 < vr) ? acc[2*i+1] : 0.f };
          G2(y);
        }
      }
    }
    float ssum = __builtin_fmaf(FXH, aX[0]+aX[1], aP[0]+aP[1]);
    ssum += __shfl_xor(ssum, 32);
    if (lane < 32){
      size_t o = (size_t)g*1024 + col;
      unsigned short h = f2bf(ssum);
      Sh[o] = h; Sl[o] = f2bf(ssum - bf2f(h));
    }
  }
}

// ========== kg: GEMM, A/B pre-split bf16 hi/lo K-major planes; XCD-swizzled ==========
// modes: gf!=null -> G1 (plane out + gh-init fuse);
//        w3f!=null -> G3+final (gelu, dot w3, 16-lane reduce, atomicAdd out);
//        else -> G2 (gelu, plane out)
__global__ __launch_bounds__(256) void kg(
    const unsigned short* __restrict__ Ah, const unsigned short* __restrict__ Al,
    int K, int nkc,
    const unsigned short* __restrict__ Bh, const unsigned short* __restrict__ Bl,
    const float* __restrict__ gf, const int* __restrict__ nstart, const int* __restrict__ cnt,
    const float* __restrict__ b2n, const float* __restrict__ b2e,
    const float* __restrict__ bias, const float* __restrict__ gam, const float* __restrict__ bet,
    unsigned short* __restrict__ Oh, unsigned short* __restrict__ Ol,
    const float* __restrict__ w3f, float* __restrict__ outp){
  const int t = threadIdx.x, lane = t & 63, w = t >> 6;
  const int q = lane >> 4, m = lane & 15;
  // bijective XCD swizzle (nwg = 32*16 = 512, divisible by 8)
  const int flat = blockIdx.y*32 + blockIdx.x;
  const int swz = (flat & 7)*64 + (flat >> 3);
  const int c0 = (swz & 31)*16, r0 = (swz >> 5)*64 + w*16;
  f32x4 acc = {0.f,0.f,0.f,0.f};
  const unsigned short* ahp = Ah + (size_t)(r0 + m)*K + (q<<3);
  const unsigned short* alp = Al + (size_t)(r0 + m)*K + (q<<3);
  const unsigned short* bhp = Bh + (size_t)(c0 + m)*K + (q<<3);
  const unsigned short* blp = Bl + (size_t)(c0 + m)*K + (q<<3);
#pragma unroll 2
  for (int kc = 0; kc < nkc; ++kc){
    const int ko = kc*32;
    short8 ah = *(const short8*)(ahp + ko);
    short8 al = *(const short8*)(alp + ko);
    short8 bh = *(const short8*)(bhp + ko);
    short8 bl = *(const short8*)(blp + ko);
    acc = __builtin_amdgcn_mfma_f32_16x16x32_bf16(ah, bh, acc, 0, 0, 0);
    acc = __builtin_amdgcn_mfma_f32_16x16x32_bf16(ah, bl, acc, 0, 0, 0);
    acc = __builtin_amdgcn_mfma_f32_16x16x32_bf16(al, bh, acc, 0, 0, 0);
  }
  const float rs = 0.99999500003750f;
  const int c = c0 + m;
  if (gf){
    const float bnv = b2n[c], bev = b2e[c];
#pragma unroll
    for (int i=0;i<4;++i){
      int r = r0 + q*4 + i;
      float cn = (float)(nstart[r+1] - nstart[r]);
      float ce = (float)min(cnt[r], ES);
      float v = acc[i] + gf[(size_t)r*HH + c] + cn*bnv + ce*bev;
      unsigned short h = f2bf(v);
      Oh[(size_t)r*HH + c] = h;
      Ol[(size_t)r*HH + c] = f2bf(v - bf2f(h));
    }
  } else if (w3f){
    // G3 + fused final: partial dot over this block's 16 cols, reduce, atomic add
    const float sc = gam[c]*rs, bi = bias[c], be = bet[c];
    const float w0 = w3f[2*c], w1 = w3f[2*c+1];
#pragma unroll
    for (int i=0;i<4;++i){
      int r = r0 + q*4 + i;
      float v = gelu_f((acc[i] + bi)*sc + be);
      float p0 = v*w0, p1 = v*w1;
      p0 += __shfl_xor(p0, 1); p0 += __shfl_xor(p0, 2);
      p0 += __shfl_xor(p0, 4); p0 += __shfl_xor(p0, 8);
      p1 += __shfl_xor(p1, 1); p1 += __shfl_xor(p1, 2);
      p1 += __shfl_xor(p1, 4); p1 += __shfl_xor(p1, 8);
      if (m == 0){
        atomicAdd(&outp[r*2],   p0);
        atomicAdd(&outp[r*2+1], p1);
      }
    }
  } else {
    const float sc = gam[c]*rs, bi = bias[c], be = bet[c];
#pragma unroll
    for (int i=0;i<4;++i){
      int r = r0 + q*4 + i;
      float v = gelu_f((acc[i] + bi)*sc + be);
      unsigned short h = f2bf(v);
      Oh[(size_t)r*HH + c] = h;
      Ol[(size_t)r*HH + c] = f2bf(v - bf2f(h));
    }
  }
}

extern "C" void kernel_launch(void* const* d_in, const int* in_sizes, int n_in,
                              void* d_out, int out_size, void* d_ws, size_t ws_size,
                              hipStream_t stream) {
  const float* nf    = (const float*)d_in[0];
  const float* ef    = (const float*)d_in[1];
  const float* gf    = (const float*)d_in[2];
  const float* dp    = (const float*)d_in[3];
  const int*   ny    = (const int*)d_in[4];
  const int*   bidx  = (const int*)d_in[5];
  const int*   eidx  = (const int*)d_in[6];
  const float* nfw1  = (const float*)d_in[7];
  const float* nfb1  = (const float*)d_in[8];
  const float* nfg1  = (const float*)d_in[9];
  const float* nfbe1 = (const float*)d_in[10];
  const float* w2n   = (const float*)d_in[11];
  const float* b2n   = (const float*)d_in[12];
  const float* efw1  = (const float*)d_in[13];
  const float* efb1  = (const float*)d_in[14];
  const float* efg1  = (const float*)d_in[15];
  const float* efbe1 = (const float*)d_in[16];
  const float* w2e   = (const float*)d_in[17];
  const float* b2e   = (const float*)d_in[18];
  const float* ow1   = (const float*)d_in[19];
  const float* ob1   = (const float*)d_in[20];
  const float* og1   = (const float*)d_in[21];
  const float* obe1  = (const float*)d_in[22];
  const float* ow2   = (const float*)d_in[23];
  const float* ob2   = (const float*)d_in[24];
  const float* og2   = (const float*)d_in[25];
  const float* obe2  = (const float*)d_in[26];
  const float* ow3   = (const float*)d_in[27];
  const float* ob3   = (const float*)d_in[28];

  // Host-side deg-6 Chebyshev fit of G(u)=0.5*sqrt(u)*erf(sqrt(u/2)) on u in [0,6.25],
  // monomial coeffs in s = u/3.125 - 1, with P(-1) forced to 0. Computed once.
  static float MC[7];
  static bool inited = false;
  if (!inited){
    const double PI = 3.14159265358979323846;
    double th[7], fj[7];
    for (int j=0;j<7;++j){
      th[j] = PI*((double)j + 0.5)/7.0;
      double u = 3.125*(cos(th[j]) + 1.0);
      double v = sqrt(u);
      fj[j] = 0.5*v*erf(v*0.70710678118654752);
    }
    double c[7];
    for (int k=0;k<7;++k){
      double sm = 0.0;
      for (int j=0;j<7;++j) sm += fj[j]*cos((double)k*th[j]);
      c[k] = 2.0*sm/7.0;
    }
    c[0] *= 0.5;
    const double T[7][7] = {
      { 1, 0,  0,  0,   0,  0,  0},
      { 0, 1,  0,  0,   0,  0,  0},
      {-1, 0,  2,  0,   0,  0,  0},
      { 0,-3,  0,  4,   0,  0,  0},
      { 1, 0, -8,  0,   8,  0,  0},
      { 0, 5,  0,-20,   0, 16,  0},
      {-1, 0, 18,  0, -48,  0, 32}};
    double m[7] = {0,0,0,0,0,0,0};
    for (int k=0;k<7;++k)
      for (int i=0;i<7;++i) m[i] += c[k]*T[k][i];
    double p1 = m[0]-m[1]+m[2]-m[3]+m[4]-m[5]+m[6];
    m[0] -= p1;
    for (int i=0;i<7;++i) MC[i] = (float)m[i];
    inited = true;
  }

  unsigned char* p = (unsigned char*)d_ws;
  unsigned short* Sh = (unsigned short*)p;   p += (size_t)NG*1024*2;  // 2MB
  unsigned short* Sl = (unsigned short*)p;   p += (size_t)NG*1024*2;  // 2MB
  unsigned short* efs = (unsigned short*)p;  p += ((size_t)NG*ES + 64)*16*2; // 28.7MB (+pad)
  unsigned short* nf48 = (unsigned short*)p; p += (size_t)NN*48*2;    // 19.2MB (reused)
  unsigned short* Bh1 = (unsigned short*)p;  p += (size_t)HH*1024*2;  // 1MB
  unsigned short* Bl1 = (unsigned short*)p;  p += (size_t)HH*1024*2;  // 1MB
  unsigned short* Bh2 = (unsigned short*)p;  p += (size_t)HH*512*2;   // 0.5MB
  unsigned short* Bl2 = (unsigned short*)p;  p += (size_t)HH*512*2;
  unsigned short* Bh3 = (unsigned short*)p;  p += (size_t)HH*512*2;
  unsigned short* Bl3 = (unsigned short*)p;  p += (size_t)HH*512*2;
  unsigned short* w1n48T = (unsigned short*)p; p += 512*48*2;
  unsigned short* w1eT16 = (unsigned short*)p; p += 512*16*2;
  float* b1n_s  = (float*)p;                 p += 512*4;
  float* b1e_s  = (float*)p;                 p += 512*4;
  int* nstart   = (int*)p;                   p += 1032*4;
  int* cnt      = (int*)p;                   p += NG*4;
  // eg aliases Sh+Sl region (2.4MB < 4MB; eg dead before kmain2 writes S planes)
  int* eg = (int*)Sh;
  // gh/xg planes alias nf48 region (dead after kmain2; 4MB < 19.2MB)
  unsigned short* ghh = (unsigned short*)nf48;
  unsigned short* ghl = ghh + (size_t)NG*HH;
  unsigned short* xgh = ghl + (size_t)NG*HH;
  unsigned short* xgl = xgh + (size_t)NG*HH;

  kpre<<<1825, 256, 0, stream>>>(nfw1, nfb1, nfg1, nfbe1, efw1, efb1, efg1, efbe1,
                                 w2n, w2e, ow1, ow2, ob3, (float*)d_out,
                                 w1n48T, w1eT16, b1n_s, b1e_s, bidx, nstart, cnt,
                                 nf, dp, ny, nf48,
                                 Bh1, Bl1, Bh2, Bl2, Bh3, Bl3);
  kscatter<<<64, 1024, 0, stream>>>(eidx, bidx, ef, eg, cnt, efs);
  kmain2<<<4096, 512, 0, stream>>>(efs, cnt, w1eT16, b1e_s,
                                   nf48, nstart, w1n48T, b1n_s,
                                   MC[0], MC[1], MC[2], MC[3], MC[4], MC[5], MC[6],
                                   Sh, Sl);
  // G1: gh = S @ [w2n;w2e] + gf + cn*b2n + ce*b2e   (bf16-plane out)
  kg<<<dim3(32,16), 256, 0, stream>>>(Sh, Sl, 1024, 32, Bh1, Bl1,
                                      gf, nstart, cnt, b2n, b2e,
                                      nullptr, nullptr, nullptr, ghh, ghl,
                                      nullptr, nullptr);
  // G2: xg = gelu(bn(gh @ ow1 + ob1))   (bf16-plane out)
  kg<<<dim3(32,16), 256, 0, stream>>>(ghh, ghl, 512, 16, Bh2, Bl2,
                                      nullptr, nullptr, nullptr, nullptr, nullptr,
                                      ob1, og1, obe1, xgh, xgl,
                                      nullptr, nullptr);
  // G3 + final: out += gelu(bn(xg @ ow2 + ob2)) @ ow3   (bias pre-loaded by kpre)
  kg<<<dim3(32,16), 256, 0, stream>>>(xgh, xgl, 512, 16, Bh3, Bl3,
                                      nullptr, nullptr, nullptr, nullptr, nullptr,
                                      ob2, og2, obe2, nullptr, nullptr,
                                      ow3, (float*)d_out);
}

// Round 11
// 335.121 us; speedup vs baseline: 1.1182x; 1.1182x over previous
//
#include <hip/hip_runtime.h>
#include <hip/hip_bf16.h>
#include <cmath>

#define NN 200000
#define NE 600000
#define NG 1024
#define HH 512
#define ECAP 1024

typedef short short8 __attribute__((ext_vector_type(8)));
typedef float f32x4 __attribute__((ext_vector_type(4)));
typedef float f32x2 __attribute__((ext_vector_type(2)));
typedef float f32x16 __attribute__((ext_vector_type(16)));

__device__ __forceinline__ unsigned short f2bf(float f){
  unsigned u = __float_as_uint(f);
  u += 0x7fffu + ((u >> 16) & 1u);
  return (unsigned short)(u >> 16);
}
__device__ __forceinline__ float bf2f(unsigned short h){
  return __uint_as_float(((unsigned)h) << 16);
}

// packed f32x8 -> bf16x8 (RTNE)
__device__ __forceinline__ short8 cvt8pk(float4 a, float4 b){
  union { short8 s; __hip_bfloat162 h[4]; } u;
  u.h[0] = __float22bfloat162_rn(make_float2(a.x, a.y));
  u.h[1] = __float22bfloat162_rn(make_float2(a.z, a.w));
  u.h[2] = __float22bfloat162_rn(make_float2(b.x, b.y));
  u.h[3] = __float22bfloat162_rn(make_float2(b.z, b.w));
  return u.s;
}

// f32x8 -> bf16 hi + bf16 lo (split-precision) — kgemm3 only
__device__ __forceinline__ void split8(const float* v, short8* hi, short8* lo){
  union { short8 s; __hip_bfloat162 h[4]; unsigned u[4]; } H, L;
#pragma unroll
  for (int p=0;p<4;++p){
    float a = v[2*p], b = v[2*p+1];
    H.h[p] = __float22bfloat162_rn(make_float2(a, b));
    unsigned hu = H.u[p];
    L.h[p] = __float22bfloat162_rn(make_float2(a - __uint_as_float(hu << 16),
                                               b - __uint_as_float(hu & 0xffff0000u)));
  }
  *hi = H.s; *lo = L.s;
}

// analytic gelu (GEMM epilogues only — 1M elements total)
__device__ __forceinline__ float gelu_f(float x){
  float p = __builtin_fmaf(x*x, -0.10294325f, -2.3022085f);
  float e = __builtin_amdgcn_exp2f(x * p);
  return x * __builtin_amdgcn_rcpf(1.0f + e);
}

// ---- packed fp32 (VOP3P; rate-neutral vs scalar but halves inst count) ----
#define PKFMA3(d,a,b,c) asm("v_pk_fma_f32 %0, %1, %2, %3" : "=v"(d) : "v"(a), "v"(b), "v"(c))
#define PKFMA_IP(p,s,k) asm("v_pk_fma_f32 %0, %0, %1, %2" : "+v"(p) : "v"(s), "v"(k))
#define PKADD_IP(d,a)   asm("v_pk_add_f32 %0, %0, %1"     : "+v"(d) : "v"(a))

// gelu accumulate; bias already inside y (folded into MFMA C operand).
//   y = x*ISQ (pre-scaled);  s = y^2-1;  P(s)=G(x^2), P(-1)=0
//   aX += y; aP += P.  Final: sum gelu = FXH*aX + aP
#define G2(y_) { \
  f32x2 s_; PKFMA3(s_, y_, y_, n1); \
  f32x2 p_; PKFMA3(p_, s_, K6, K5); \
  PKFMA_IP(p_, s_, K4); PKFMA_IP(p_, s_, K3); \
  PKFMA_IP(p_, s_, K2); PKFMA_IP(p_, s_, K1); \
  PKFMA_IP(p_, s_, K0); \
  PKADD_IP(aX, y_); PKADD_IP(aP, p_); }

#define COEFS \
  const f32x2 K0 = {c0,c0}, K1 = {c1,c1}, K2 = {c2,c2}, K3 = {c3,c3}; \
  const f32x2 K4 = {c4,c4}, K5 = {c5,c5}, K6 = {c6,c6}; \
  const f32x2 n1 = {-1.f,-1.f};

#define ISQ 0.56568542494924f    // sqrt(2)/2.5 : y = x*ISQ, s=y^2-1 spans x^2 in [0,6.25]
#define FXH 0.88388347648318f    // 0.5x = FXH*y

// ========== kpre: R5 structure ==========
// b<2: w1eT16 + b1e_s ; b<4: w1n48T + b1n_s ; b<786: nstart ;
// b==786: cnt zero ; 787..1568: nf48 prepack ; 1569..3912: efb prepack
__global__ __launch_bounds__(256) void kpre(
    const float* __restrict__ nfw1, const float* __restrict__ nfb1,
    const float* __restrict__ nfg1, const float* __restrict__ nfbe1,
    const float* __restrict__ efw1, const float* __restrict__ efb1,
    const float* __restrict__ efg1, const float* __restrict__ efbe1,
    unsigned short* __restrict__ w1n48T, unsigned short* __restrict__ w1eT16,
    float* __restrict__ b1n_s, float* __restrict__ b1e_s,
    const int* __restrict__ bidx, int* __restrict__ nstart,
    int* __restrict__ cnt,
    const float* __restrict__ nf, const float* __restrict__ dp,
    const int* __restrict__ ny, const float* __restrict__ ef,
    unsigned short* __restrict__ nf48, unsigned short* __restrict__ efb){
  const float rs = 0.99999500003750f;   // 1/sqrt(1+1e-5)
  int b = blockIdx.x, t = threadIdx.x;
  if (b < 2){
    int c = b*256 + t;
    float sc = efg1[c]*rs*ISQ;
#pragma unroll
    for (int k=0;k<16;++k) w1eT16[c*16+k] = f2bf(efw1[k*HH+c]*sc);
    b1e_s[c] = (efb1[c]*efg1[c]*rs + efbe1[c])*ISQ;
  } else if (b < 4){
    int c = (b-2)*256 + t;
    float sc = nfg1[c]*rs*ISQ;
#pragma unroll
    for (int k=0;k<48;++k)
      w1n48T[c*48+k] = (k < 41) ? f2bf(nfw1[k*HH+c]*sc) : (unsigned short)0;
    b1n_s[c] = (nfb1[c]*nfg1[c]*rs + nfbe1[c])*ISQ;
  } else if (b < 786){
    int i = (b-4)*256 + t;
    if (i < NN){
      int g0 = bidx[i];
      int g1 = (i+1 < NN) ? bidx[i+1] : NG;
      for (int g = g0+1; g <= g1; ++g) nstart[g] = i+1;
      if (i == 0) for (int g = 0; g <= g0; ++g) nstart[g] = 0;
    }
  } else if (b == 786){
    cnt[t] = 0; cnt[t+256] = 0; cnt[t+512] = 0; cnt[t+768] = 0;
  } else if (b < 1569){
    // nf48: [0..31]=nf, [32..40]=onehot(ny)*dp, [41..47]=0
    int r = (b-787)*256 + t;
    if (r < NN){
      const float4* ap = (const float4*)(nf + (size_t)r*32);
      unsigned short v[48];
      union { short8 s; unsigned short u[8]; } cv;
#pragma unroll
      for (int p2=0; p2<4; ++p2){
        cv.s = cvt8pk(ap[2*p2], ap[2*p2+1]);
#pragma unroll
        for (int j=0;j<8;++j) v[p2*8+j] = cv.u[j];
      }
      unsigned short db = f2bf(dp[r]);
      int cls = ny[r];
#pragma unroll
      for (int j=0;j<9;++j) v[32+j] = (cls==j) ? db : (unsigned short)0;
#pragma unroll
      for (int j=41;j<48;++j) v[j] = 0;
      unsigned short* op = nf48 + (size_t)r*48;
#pragma unroll
      for (int p2=0; p2<6; ++p2) *(short8*)(op + p2*8) = *(short8*)&v[p2*8];
    }
  } else {
    int r = (b-1569)*256 + t;
    if (r < NE){
      const float4* ap = (const float4*)(ef + (size_t)r*16);
      unsigned short* op = efb + (size_t)r*16;
      *(short8*)op       = cvt8pk(ap[0], ap[1]);
      *(short8*)(op + 8) = cvt8pk(ap[2], ap[3]);
    }
  }
}

// ========== kscatter: two-level scatter (R5 exact) ==========
__global__ __launch_bounds__(1024) void kscatter(const int* __restrict__ eidx,
    const int* __restrict__ bidx, int* __restrict__ eg,
    int* __restrict__ cnt, int* __restrict__ perm2d){
  __shared__ int h[NG];
  __shared__ int base[NG];
  const int b = blockIdx.x, t = threadIdx.x;
  h[t] = 0;
  __syncthreads();
  const int per = NE / 64;            // 9375, exact
  const int lo = b*per, hi = lo + per;
  for (int e = lo + t; e < hi; e += 1024){
    int g = bidx[eidx[e]];
    eg[e] = g;
    atomicAdd(&h[g], 1);
  }
  __syncthreads();
  int c = h[t];
  if (c > 0) base[t] = atomicAdd(&cnt[t], c);
  h[t] = 0;
  __syncthreads();
  for (int e = lo + t; e < hi; e += 1024){
    int g = eg[e];
    int p = base[g] + atomicAdd(&h[g], 1);
    if (p < ECAP) perm2d[(g << 10) + p] = e;
  }
}

// ========== kedge: R5 LDS-staged structure + bias-in-C + deg-6 pk gelu ==========
// 2 blocks/graph, 8 waves x 32 cols; wave-0 stages 32 edges/chunk into LDS
__global__ __launch_bounds__(512) void kedge(
    const unsigned short* __restrict__ efb, const int* __restrict__ perm2d,
    const int* __restrict__ cnt, const unsigned short* __restrict__ w1eT16,
    const float* __restrict__ b1e_s,
    float c0, float c1, float c2, float c3, float c4, float c5, float c6,
    float* __restrict__ S){
  __shared__ short lds[2][32*40];      // stride 40 shorts (80B) per edge row
  const int t = threadIdx.x;
  const int lane = t & 63, wid = t >> 6;
  const int hi = lane >> 5;
  const int g = blockIdx.x >> 1;
  const int col = ((blockIdx.x & 1) << 8) + (wid << 5) + (lane & 31);
  COEFS;
  short8 bfr = *(const short8*)(w1eT16 + col*16 + (hi<<3));
  const float bv = b1e_s[col];
  f32x16 bias16;
#pragma unroll
  for (int i=0;i<16;++i) bias16[i] = bv;
  f32x2 aX = {0.f,0.f}, aP = {0.f,0.f};
  const int s1 = min(cnt[g], ECAP);
  if (s1 > 0){
    const int base = g << 10;
    const int nch = (s1 + 31) >> 5;
    short8 a1;
    if (t < 64){
      int r0 = min(t & 31, s1-1);
      int r1 = min(32 + (t & 31), s1-1);
      int e0 = perm2d[base + r0];
      int e1 = perm2d[base + r1];
      short8 a0 = *(const short8*)(efb + (size_t)e0*16 + ((t>>5)<<3));
      *(short8*)&lds[0][(t&31)*40 + ((t>>5)<<3)] = a0;
      a1 = *(const short8*)(efb + (size_t)e1*16 + ((t>>5)<<3));
    }
    __syncthreads();
    for (int ch=0; ch<nch; ++ch){
      short8 af = *(const short8*)&lds[ch&1][(lane&31)*40 + (hi<<3)];
      if (t < 64){
        if (ch+1 < nch) *(short8*)&lds[(ch+1)&1][(t&31)*40 + ((t>>5)<<3)] = a1;
        int r2 = min((ch+2)*32 + (t & 31), s1-1);
        int e2 = perm2d[base + r2];
        a1 = *(const short8*)(efb + (size_t)e2*16 + ((t>>5)<<3));
      }
      __syncthreads();
      f32x16 acc = __builtin_amdgcn_mfma_f32_32x32x16_bf16(af, bfr, bias16, 0, 0, 0);
      const int vr = s1 - ch*32;
      if (vr >= 32){
#pragma unroll
        for (int i=0;i<8;++i){
          f32x2 y = {acc[2*i], acc[2*i+1]};
          G2(y);
        }
      } else {
#pragma unroll
        for (int i=0;i<8;++i){
          int r0 = ((2*i)&3) + (((2*i)>>2)<<3) + (hi<<2);
          f32x2 y = { (r0 < vr) ? acc[2*i] : 0.f,
                      (r0+1 < vr) ? acc[2*i+1] : 0.f };
          G2(y);
        }
      }
    }
  }
  float ssum = __builtin_fmaf(FXH, aX[0]+aX[1], aP[0]+aP[1]);
  ssum += __shfl_xor(ssum, 32);
  if (lane < 32) S[(size_t)g*1024 + 512 + col] = ssum;
}

// ========== knode: R5 structure + bias-in-C + deg-6 pk gelu ==========
// 4 blocks/graph, 4 waves x 32 cols, K=48 (3 chained MFMAs), contiguous rows
__global__ __launch_bounds__(256) void knode(
    const unsigned short* __restrict__ nf48, const int* __restrict__ nstart,
    const unsigned short* __restrict__ w1n48T, const float* __restrict__ b1n_s,
    float c0, float c1, float c2, float c3, float c4, float c5, float c6,
    float* __restrict__ S){
  const int t = threadIdx.x;
  const int lane = t & 63, wid = t >> 6;
  const int hi = lane >> 5;
  const int g = blockIdx.x >> 2;
  const int col = ((blockIdx.x & 3) << 7) + (wid << 5) + (lane & 31);
  COEFS;
  const unsigned short* bp = w1n48T + col*48 + (hi<<3);
  short8 bf0 = *(const short8*)(bp);
  short8 bf1 = *(const short8*)(bp + 16);
  short8 bf2 = *(const short8*)(bp + 32);
  const float bv = b1n_s[col];
  f32x16 bias16;
#pragma unroll
  for (int i=0;i<16;++i) bias16[i] = bv;
  f32x2 aX = {0.f,0.f}, aP = {0.f,0.f};
  const int s0r = nstart[g], s1 = nstart[g+1];
  const int nch = (s1 - s0r + 31) >> 5;
  for (int ch=0; ch<nch; ++ch){
    const int rb = s0r + ch*32;
    int ar = min(rb + (lane & 31), s1-1);
    const unsigned short* apn = nf48 + (size_t)ar*48 + (hi<<3);
    short8 a0 = *(const short8*)(apn);
    short8 a1 = *(const short8*)(apn + 16);
    short8 a2 = *(const short8*)(apn + 32);
    f32x16 acc = __builtin_amdgcn_mfma_f32_32x32x16_bf16(a0, bf0, bias16, 0, 0, 0);
    acc = __builtin_amdgcn_mfma_f32_32x32x16_bf16(a1, bf1, acc, 0, 0, 0);
    acc = __builtin_amdgcn_mfma_f32_32x32x16_bf16(a2, bf2, acc, 0, 0, 0);
    const int vr = s1 - rb;
    if (vr >= 32){
#pragma unroll
      for (int i=0;i<8;++i){
        f32x2 y = {acc[2*i], acc[2*i+1]};
        G2(y);
      }
    } else {
#pragma unroll
      for (int i=0;i<8;++i){
        int r0 = ((2*i)&3) + (((2*i)>>2)<<3) + (hi<<2);
        f32x2 y = { (r0 < vr) ? acc[2*i] : 0.f,
                    (r0+1 < vr) ? acc[2*i+1] : 0.f };
        G2(y);
      }
    }
  }
  float ssum = __builtin_fmaf(FXH, aX[0]+aX[1], aP[0]+aP[1]);
  ssum += __shfl_xor(ssum, 32);
  if (lane < 32) S[(size_t)g*1024 + col] = ssum;
}

// ========== kgemm3: R5 exact — LDS-free split GEMM, B direct from fp32 weights ========
// G1 mode (gf!=null): out = acc + gf + cn*b2n + ce*b2e ; else gelu(bn(acc+bias))
__global__ __launch_bounds__(256) void kgemm3(const float* __restrict__ A, int lda, int nkc,
    const float* __restrict__ B0, const float* __restrict__ B1,
    float* __restrict__ out,
    const float* __restrict__ gf, const int* __restrict__ nstart, const int* __restrict__ cnt,
    const float* __restrict__ b2n, const float* __restrict__ b2e,
    const float* __restrict__ bias, const float* __restrict__ gam, const float* __restrict__ bet){
  const int t = threadIdx.x, lane = t & 63, w = t >> 6;
  const int q = lane >> 4, m = lane & 15;
  const int c0 = blockIdx.x*16, r0 = blockIdx.y*64 + w*16;
  f32x4 acc = {0.f,0.f,0.f,0.f};
  const float* ap = A + (size_t)(r0 + m)*lda + (q<<3);
  for (int kc = 0; kc < nkc; ++kc){
    const int ko = kc*32;
    float4 x = *(const float4*)(ap + ko);
    float4 y = *(const float4*)(ap + ko + 4);
    float v[8] = {x.x,x.y,x.z,x.w,y.x,y.y,y.z,y.w};
    short8 ah, al;
    split8(v, &ah, &al);
    const float* Bp = (kc < 16) ? B0 : B1;
    const float* bp = Bp + (size_t)((kc & 15)*32 + (q<<3))*HH + c0 + m;
    float bvv[8];
#pragma unroll
    for (int j=0;j<8;++j) bvv[j] = bp[(size_t)j*HH];
    short8 bh, bl;
    split8(bvv, &bh, &bl);
    acc = __builtin_amdgcn_mfma_f32_16x16x32_bf16(ah, bh, acc, 0, 0, 0);
    acc = __builtin_amdgcn_mfma_f32_16x16x32_bf16(ah, bl, acc, 0, 0, 0);
    acc = __builtin_amdgcn_mfma_f32_16x16x32_bf16(al, bh, acc, 0, 0, 0);
  }
  const float rs = 0.99999500003750f;
  const int c = c0 + m;
  if (gf){
    const float bnv = b2n[c], bev = b2e[c];
#pragma unroll
    for (int i=0;i<4;++i){
      int r = r0 + q*4 + i;
      float cn = (float)(nstart[r+1] - nstart[r]);
      float ce = (float)cnt[r];
      out[(size_t)r*HH + c] = acc[i] + gf[(size_t)r*HH + c] + cn*bnv + ce*bev;
    }
  } else {
    const float sc = gam[c]*rs, bi = bias[c], be = bet[c];
#pragma unroll
    for (int i=0;i<4;++i){
      int r = r0 + q*4 + i;
      out[(size_t)r*HH + c] = gelu_f((acc[i] + bi)*sc + be);
    }
  }
}

// ========== final 512 -> 2 linear (R5 exact) ==========
__global__ __launch_bounds__(256) void kfinal(const float* __restrict__ x2, const float* __restrict__ w3,
    const float* __restrict__ b3, float* __restrict__ out){
  const int lane = threadIdx.x & 63, wv = threadIdx.x >> 6;
  const int r = blockIdx.x*4 + wv;
  float a0 = 0.f, a1 = 0.f;
#pragma unroll
  for (int tt=0; tt<8; ++tt){
    int k = lane + tt*64;
    float x = x2[(size_t)r*HH + k];
    a0 = __builtin_fmaf(x, w3[2*k], a0);
    a1 = __builtin_fmaf(x, w3[2*k+1], a1);
  }
#pragma unroll
  for (int d=1; d<64; d<<=1){ a0 += __shfl_xor(a0, d); a1 += __shfl_xor(a1, d); }
  if (lane == 0){ out[r*2] = a0 + b3[0]; out[r*2+1] = a1 + b3[1]; }
}

extern "C" void kernel_launch(void* const* d_in, const int* in_sizes, int n_in,
                              void* d_out, int out_size, void* d_ws, size_t ws_size,
                              hipStream_t stream) {
  const float* nf    = (const float*)d_in[0];
  const float* ef    = (const float*)d_in[1];
  const float* gf    = (const float*)d_in[2];
  const float* dp    = (const float*)d_in[3];
  const int*   ny    = (const int*)d_in[4];
  const int*   bidx  = (const int*)d_in[5];
  const int*   eidx  = (const int*)d_in[6];
  const float* nfw1  = (const float*)d_in[7];
  const float* nfb1  = (const float*)d_in[8];
  const float* nfg1  = (const float*)d_in[9];
  const float* nfbe1 = (const float*)d_in[10];
  const float* w2n   = (const float*)d_in[11];
  const float* b2n   = (const float*)d_in[12];
  const float* efw1  = (const float*)d_in[13];
  const float* efb1  = (const float*)d_in[14];
  const float* efg1  = (const float*)d_in[15];
  const float* efbe1 = (const float*)d_in[16];
  const float* w2e   = (const float*)d_in[17];
  const float* b2e   = (const float*)d_in[18];
  const float* ow1   = (const float*)d_in[19];
  const float* ob1   = (const float*)d_in[20];
  const float* og1   = (const float*)d_in[21];
  const float* obe1  = (const float*)d_in[22];
  const float* ow2   = (const float*)d_in[23];
  const float* ob2   = (const float*)d_in[24];
  const float* og2   = (const float*)d_in[25];
  const float* obe2  = (const float*)d_in[26];
  const float* ow3   = (const float*)d_in[27];
  const float* ob3   = (const float*)d_in[28];

  // Host-side deg-6 Chebyshev fit of G(u)=0.5*sqrt(u)*erf(sqrt(u/2)) on u in [0,6.25],
  // monomial coeffs in s = u/3.125 - 1, with P(-1) forced to 0. Computed once.
  static float MC[7];
  static bool inited = false;
  if (!inited){
    const double PI = 3.14159265358979323846;
    double th[7], fj[7];
    for (int j=0;j<7;++j){
      th[j] = PI*((double)j + 0.5)/7.0;
      double u = 3.125*(cos(th[j]) + 1.0);
      double v = sqrt(u);
      fj[j] = 0.5*v*erf(v*0.70710678118654752);
    }
    double c[7];
    for (int k=0;k<7;++k){
      double sm = 0.0;
      for (int j=0;j<7;++j) sm += fj[j]*cos((double)k*th[j]);
      c[k] = 2.0*sm/7.0;
    }
    c[0] *= 0.5;
    const double T[7][7] = {
      { 1, 0,  0,  0,   0,  0,  0},
      { 0, 1,  0,  0,   0,  0,  0},
      {-1, 0,  2,  0,   0,  0,  0},
      { 0,-3,  0,  4,   0,  0,  0},
      { 1, 0, -8,  0,   8,  0,  0},
      { 0, 5,  0,-20,   0, 16,  0},
      {-1, 0, 18,  0, -48,  0, 32}};
    double m[7] = {0,0,0,0,0,0,0};
    for (int k=0;k<7;++k)
      for (int i=0;i<7;++i) m[i] += c[k]*T[k][i];
    double p1 = m[0]-m[1]+m[2]-m[3]+m[4]-m[5]+m[6];
    m[0] -= p1;
    for (int i=0;i<7;++i) MC[i] = (float)m[i];
    inited = true;
  }

  unsigned char* p = (unsigned char*)d_ws;
  float* S      = (float*)p;                 p += (size_t)NG*1024*4;  // 4MB
  int*   perm2d = (int*)p;                   p += (size_t)NG*ECAP*4;  // 4MB
  unsigned short* nf48 = (unsigned short*)p; p += (size_t)NN*48*2;    // 19.2MB (reused)
  unsigned short* efb  = (unsigned short*)p; p += (size_t)NE*16*2;    // 19.2MB
  unsigned short* w1n48T = (unsigned short*)p; p += 512*48*2;
  unsigned short* w1eT16 = (unsigned short*)p; p += 512*16*2;
  float* b1n_s  = (float*)p;                 p += 512*4;
  float* b1e_s  = (float*)p;                 p += 512*4;
  int* nstart   = (int*)p;                   p += 1032*4;
  int* cnt      = (int*)p;                   p += NG*4;
  // eg aliases S (dead before kedge/knode write S)
  int* eg = (int*)S;
  // gh/xg2/x2f alias nf48 region (dead after knode)
  float* gh  = (float*)nf48;
  float* xg2 = gh  + (size_t)NG*HH;
  float* x2f = xg2 + (size_t)NG*HH;

  kpre<<<3913, 256, 0, stream>>>(nfw1, nfb1, nfg1, nfbe1, efw1, efb1, efg1, efbe1,
                                 w1n48T, w1eT16, b1n_s, b1e_s, bidx, nstart, cnt,
                                 nf, dp, ny, ef, nf48, efb);
  kscatter<<<64, 1024, 0, stream>>>(eidx, bidx, eg, cnt, perm2d);
  kedge<<<2048, 512, 0, stream>>>(efb, perm2d, cnt, w1eT16, b1e_s,
                                  MC[0], MC[1], MC[2], MC[3], MC[4], MC[5], MC[6], S);
  knode<<<4096, 256, 0, stream>>>(nf48, nstart, w1n48T, b1n_s,
                                  MC[0], MC[1], MC[2], MC[3], MC[4], MC[5], MC[6], S);
  // G1: gh = S @ [w2n;w2e] + gf + cn*b2n + ce*b2e
  kgemm3<<<dim3(32,16), 256, 0, stream>>>(S, 1024, 32, w2n, w2e, gh,
                                          gf, nstart, cnt, b2n, b2e,
                                          nullptr, nullptr, nullptr);
  // G2: xg2 = gelu(bn(gh @ ow1 + ob1))
  kgemm3<<<dim3(32,16), 256, 0, stream>>>(gh, 512, 16, ow1, ow1, xg2,
                                          nullptr, nullptr, nullptr, nullptr, nullptr,
                                          ob1, og1, obe1);
  // G3: x2f = gelu(bn(xg2 @ ow2 + ob2))
  kgemm3<<<dim3(32,16), 256, 0, stream>>>(xg2, 512, 16, ow2, ow2, x2f,
                                          nullptr, nullptr, nullptr, nullptr, nullptr,
                                          ob2, og2, obe2);
  kfinal<<<NG/4, 256, 0, stream>>>(x2f, ow3, ob3, (float*)d_out);
}